// Round 14
// baseline (346.168 us; speedup 1.0000x reference)
//
#include <hip/hip_runtime.h>
#include <cstdint>
#include <cstddef>

// ---------------------------------------------------------------------------
// 4-layer GCN autoencoder, pull-based propagation + MFMA fp16 GEMMs.
// CSR built per launch with a 2-level counting sort (block-aggregated coarse
// scatter -> per-bucket LDS counting sort, u16 esrc).
// Propagation: out[d] = dinv[d]*sum_{s in N(d)u{d}} (dinv[s]*h[s]) (+b, relu);
// rows pre-scaled by dinv in the producer epilogue. All gathered/GEMM-input
// intermediates are fp16 (gather is L2-miss-byte-bound); accum fp32.
// GEMM (R13): two-phase (load-all -> MFMA-all) PINNED with
// __builtin_amdgcn_sched_barrier(0). R12's unfenced version was re-scheduled
// by the compiler back to interleaved (VGPR_Count=40, ~3 loads in flight,
// L3-latency-bound at 54us). The fence forces all ST*(1+NT) load results
// live -> ~24 1KB loads in flight per wave -> latency hidden.
// ---------------------------------------------------------------------------

static inline int cdiv(int a, int b) { return (a + b - 1) / b; }

typedef _Float16 half8v __attribute__((ext_vector_type(8)));
typedef float f32x4 __attribute__((ext_vector_type(4)));

#define NBMAX 784   // >= cdiv(50000,64)=782 buckets
#define SCHUNK 8192 // edges per scatter block

// coarse histogram over dst>>6 with LDS aggregation
__global__ __launch_bounds__(256) void k_bhist(const int* __restrict__ dst,
                                               int* __restrict__ bh,
                                               int E, int nb, int perBlock) {
  __shared__ int h[NBMAX];
  for (int i = threadIdx.x; i < nb; i += 256) h[i] = 0;
  __syncthreads();
  int beg = blockIdx.x * perBlock;
  int end = min(beg + perBlock, E);
  for (int e = beg + threadIdx.x; e < end; e += 256)
    atomicAdd(&h[dst[e] >> 6], 1);
  __syncthreads();
  for (int i = threadIdx.x; i < nb; i += 256)
    if (h[i]) atomicAdd(&bh[i], h[i]);
}

// single-block exclusive scan of nb (<=1024) bucket sums -> boff, bcur
__global__ __launch_bounds__(256) void k_bscan(const int* __restrict__ bh,
                                               int* __restrict__ boff,
                                               int* __restrict__ bcur, int nb) {
  __shared__ int tsum[256];
  int t = threadIdx.x;
  int v[4];
  int s = 0;
#pragma unroll
  for (int i = 0; i < 4; ++i) {
    int idx = t * 4 + i;
    v[i] = (idx < nb) ? bh[idx] : 0;
    s += v[i];
  }
  tsum[t] = s;
  __syncthreads();
  int x = s;
  for (int d = 1; d < 256; d <<= 1) {
    int add = (t >= d) ? tsum[t - d] : 0;
    __syncthreads();
    x += add;
    tsum[t] = x;
    __syncthreads();
  }
  int base = x - s;  // exclusive prefix
#pragma unroll
  for (int i = 0; i < 4; ++i) {
    int idx = t * 4 + i;
    if (idx < nb) { boff[idx] = base; bcur[idx] = base; }
    base += v[i];
  }
  if (t == 255) boff[nb] = base;  // == E
}

// block-aggregated coarse scatter: one global atomic per (block,bucket)
__global__ __launch_bounds__(256) void k_bscatter(const int* __restrict__ src,
                                                  const int* __restrict__ dst,
                                                  int* __restrict__ bcur,
                                                  unsigned* __restrict__ tmp,
                                                  int E, int nb) {
  __shared__ int hist[NBMAX];
  __shared__ int base[NBMAX];
  int beg = blockIdx.x * SCHUNK;
  int end = min(beg + SCHUNK, E);
  for (int i = threadIdx.x; i < nb; i += 256) hist[i] = 0;
  __syncthreads();
  for (int e = beg + threadIdx.x; e < end; e += 256)
    atomicAdd(&hist[dst[e] >> 6], 1);
  __syncthreads();
  for (int b = threadIdx.x; b < nb; b += 256) {
    int c = hist[b];
    base[b] = c ? atomicAdd(&bcur[b], c) : 0;
    hist[b] = 0;  // reuse as local cursor
  }
  __syncthreads();
  for (int e = beg + threadIdx.x; e < end; e += 256) {
    int d = dst[e];
    int b = d >> 6;
    int lp = atomicAdd(&hist[b], 1);
    tmp[base[b] + lp] = ((unsigned)(d & 63) << 16) | (unsigned)src[e];
  }
}

// per-bucket counting sort (64 bins in LDS); emits u16 esrc, counts/offs/dinv
__global__ __launch_bounds__(256) void k_bsort(const unsigned* __restrict__ tmp,
                                               const int* __restrict__ boff,
                                               unsigned short* __restrict__ esrc,
                                               int* __restrict__ offs,
                                               int* __restrict__ counts,
                                               float* __restrict__ dinv,
                                               int N) {
  __shared__ int hist[64], cur[64];
  int b = blockIdx.x;
  int t = threadIdx.x;
  if (t < 64) hist[t] = 0;
  __syncthreads();
  int beg = boff[b], end = boff[b + 1];
  int cnt = end - beg;
  for (int i = t; i < cnt; i += 256) atomicAdd(&hist[tmp[beg + i] >> 16], 1);
  __syncthreads();
  if (t < 64) {
    int v = hist[t];
    int x = v;
#pragma unroll
    for (int d = 1; d < 64; d <<= 1) {
      int up = __shfl_up(x, d, 64);
      if (t >= d) x += up;
    }
    int ex = x - v;
    cur[t] = ex;
    int node = b * 64 + t;
    if (node < N) {
      counts[node] = v;
      offs[node] = beg + ex;
      dinv[node] = rsqrtf((float)(v + 1));
    }
  }
  __syncthreads();
  for (int i = t; i < cnt; i += 256) {
    unsigned v = tmp[beg + i];
    int pos = atomicAdd(&cur[v >> 16], 1);
    esrc[beg + pos] = (unsigned short)(v & 0xFFFFu);
  }
}

// transpose+cast all weight matrices to fp16: Wt[m][k] = (fp16)W[k][m].
// Also zeroes bh (saves a memset dispatch; completes before k_bhist).
__global__ __launch_bounds__(256) void k_prepw(const float* __restrict__ W1,
                                               const float* __restrict__ W2,
                                               const float* __restrict__ W3,
                                               const float* __restrict__ W4,
                                               _Float16* __restrict__ W1t,
                                               _Float16* __restrict__ W2t,
                                               _Float16* __restrict__ W3t,
                                               _Float16* __restrict__ W4t,
                                               int* __restrict__ bh) {
  int t = blockIdx.x * 256 + threadIdx.x;
  if (t < NBMAX) bh[t] = 0;
  if (t < 32768) {                      // W1 [256][128] -> W1t [128][256]
    int m = t >> 8, k = t & 255;
    W1t[t] = (_Float16)W1[k * 128 + m];
  } else if (t < 40960) {               // W2 [128][64] -> W2t [64][128]
    int u = t - 32768;
    int m = u >> 7, k = u & 127;
    W2t[u] = (_Float16)W2[k * 64 + m];
  } else if (t < 49152) {               // W3 [64][128] -> W3t [128][64]
    int u = t - 40960;
    int m = u >> 6, k = u & 63;
    W3t[u] = (_Float16)W3[k * 128 + m];
  } else if (t < 81920) {               // W4 [128][256] -> W4t [256][128]
    int u = t - 49152;
    int m = u >> 7, k = u & 127;
    W4t[u] = (_Float16)W4[k * 256 + m];
  }
}

// fp16-gather pull. W = halves per row (128 or 64). One wave per node.
// LPR = W/8 lanes cover a row with 16B half8 loads; GRP = 64/LPR edges per
// wave instr (4 at w128, 8 at w64); 4-deep unroll for MLP.
// Epilogue (group 0): t = dinv*acc (+bias) (relu) (*dinv); fp16 output.
template <int W, int BIAS, int RELU, int POST>
__global__ __launch_bounds__(256) void k_pull16(const _Float16* __restrict__ h,
                                                const unsigned short* __restrict__ esrc,
                                                const int* __restrict__ offs,
                                                const int* __restrict__ counts,
                                                const float* __restrict__ dinv,
                                                const float* __restrict__ bias,
                                                _Float16* __restrict__ out, int n) {
  const int LPR = W / 8;    // lanes per row: 16 (w128) / 8 (w64)
  const int GRP = 64 / LPR; // edge groups:    4        / 8
  int node = blockIdx.x * 4 + (threadIdx.x >> 6);
  if (node >= n) return;
  int lane = threadIdx.x & 63;
  int g  = lane / LPR;
  int fl = lane % LPR;
  size_t rbase = (size_t)node * W + fl * 8;

  float acc[8] = {};
  if (g == 0) {
    half8v sv = *(const half8v*)&h[rbase];  // self loop
#pragma unroll
    for (int q = 0; q < 8; ++q) acc[q] = (float)sv[q];
  }

  int beg = offs[node];
  int cnt = counts[node];
  int j = g;
  for (; j + 3 * GRP < cnt; j += 4 * GRP) {
    int s0 = esrc[beg + j];
    int s1 = esrc[beg + j + GRP];
    int s2 = esrc[beg + j + 2 * GRP];
    int s3 = esrc[beg + j + 3 * GRP];
    half8v v0 = *(const half8v*)&h[(size_t)s0 * W + fl * 8];
    half8v v1 = *(const half8v*)&h[(size_t)s1 * W + fl * 8];
    half8v v2 = *(const half8v*)&h[(size_t)s2 * W + fl * 8];
    half8v v3 = *(const half8v*)&h[(size_t)s3 * W + fl * 8];
#pragma unroll
    for (int q = 0; q < 8; ++q)
      acc[q] += ((float)v0[q] + (float)v1[q]) + ((float)v2[q] + (float)v3[q]);
  }
  for (; j < cnt; j += GRP) {
    int s = esrc[beg + j];
    half8v v = *(const half8v*)&h[(size_t)s * W + fl * 8];
#pragma unroll
    for (int q = 0; q < 8; ++q) acc[q] += (float)v[q];
  }

  // reduce partial sums across edge-groups (same fl, different g)
#pragma unroll
  for (int d = LPR; d < 64; d <<= 1) {
#pragma unroll
    for (int q = 0; q < 8; ++q) acc[q] += __shfl_xor(acc[q], d, 64);
  }

  if (g == 0) {
    float dv = dinv[node];
    float t[8];
#pragma unroll
    for (int q = 0; q < 8; ++q) t[q] = dv * acc[q];
    if (BIAS) {
#pragma unroll
      for (int q = 0; q < 8; ++q) t[q] += bias[fl * 8 + q];
    }
    if (RELU) {
#pragma unroll
      for (int q = 0; q < 8; ++q) t[q] = fmaxf(t[q], 0.f);
    }
    if (POST) {
#pragma unroll
      for (int q = 0; q < 8; ++q) t[q] *= dv;
    }
    half8v o;
#pragma unroll
    for (int q = 0; q < 8; ++q) o[q] = (_Float16)t[q];
    *(half8v*)&out[rbase] = o;
  }
}

// MFMA fp16 GEMM: C[N,M] = A[N,K] @ W[K,M] (+bias)(+relu)(*dinv[row]).
// Block = 16 rows x M cols; 4 waves col-split within block (wave w owns
// col-tiles [w*NT,(w+1)*NT), NT = M/64). Grid = cdiv(N,16); A streamed once.
// Phase 1: ALL fragments loaded to registers; sched_barrier(0) fence;
// Phase 2: all MFMAs. Fence prevents compiler load-sinking (R12 lesson).
// AF32: A is fp32, converted in-register. OUTF16: store fp16 else fp32.
template <int M, int K, int BIAS, int RELU, int SCALE, int AF32, int OUTF16>
__global__ __launch_bounds__(256) void k_gemm_mfma(const void* __restrict__ Av,
                                                   const _Float16* __restrict__ Wt,
                                                   const float* __restrict__ bias,
                                                   const float* __restrict__ dinv,
                                                   void* __restrict__ Cv, int N) {
  const int NT = M / 64;               // col-tiles per wave: 1,2,4
  const int ST = K / 32;               // k-steps: 2,4,8
  const int w  = threadIdx.x >> 6;     // wave 0..3
  const int l  = threadIdx.x & 63;
  const int lr = l & 15;               // A-row / B-col / C-col within tile
  const int lk = l >> 4;               // k-octet selector / C-row quad
  const int r0 = blockIdx.x * 16;
  int arow = r0 + lr;
  if (arow >= N) arow = N - 1;         // clamp: OOB rows never stored

  half8v a_all[ST];
  half8v b_all[ST][NT];

  // phase 1: issue every load (compile-time indices; max MLP)
#pragma unroll
  for (int s = 0; s < ST; ++s) {
    int k0 = s * 32;
    if (AF32) {
      const float* ap = &((const float*)Av)[(size_t)arow * K + k0 + lk * 8];
      float4 f0 = *(const float4*)ap;
      float4 f1 = *(const float4*)(ap + 4);
      half8v a;
      a[0] = (_Float16)f0.x; a[1] = (_Float16)f0.y;
      a[2] = (_Float16)f0.z; a[3] = (_Float16)f0.w;
      a[4] = (_Float16)f1.x; a[5] = (_Float16)f1.y;
      a[6] = (_Float16)f1.z; a[7] = (_Float16)f1.w;
      a_all[s] = a;
    } else {
      a_all[s] = *(const half8v*)&((const _Float16*)Av)[(size_t)arow * K + k0 + lk * 8];
    }
#pragma unroll
    for (int ct = 0; ct < NT; ++ct) {
      int col0 = (w * NT + ct) * 16;
      b_all[s][ct] = *(const half8v*)&Wt[(size_t)(col0 + lr) * K + k0 + lk * 8];
    }
  }

  // fence: nothing crosses -- keeps all loads issued before any MFMA,
  // forcing all load results live (high VGPR, high MLP).
  __builtin_amdgcn_sched_barrier(0);

  // phase 2: all MFMAs
  f32x4 acc[NT] = {};
#pragma unroll
  for (int s = 0; s < ST; ++s)
#pragma unroll
    for (int ct = 0; ct < NT; ++ct)
      acc[ct] = __builtin_amdgcn_mfma_f32_16x16x32_f16(a_all[s], b_all[s][ct], acc[ct], 0, 0, 0);

  // epilogue: C row = r0 + lk*4 + r, col = (w*NT+ct)*16 + lr
  float dvv[4];
  int okr[4];
#pragma unroll
  for (int r = 0; r < 4; ++r) {
    int ro = r0 + lk * 4 + r;
    okr[r] = (ro < N);
    dvv[r] = (SCALE && okr[r]) ? dinv[ro] : 1.0f;
  }
#pragma unroll
  for (int ct = 0; ct < NT; ++ct) {
    int col = (w * NT + ct) * 16 + lr;
    float bs = BIAS ? bias[col] : 0.f;
#pragma unroll
    for (int r = 0; r < 4; ++r) {
      if (!okr[r]) continue;
      int ro = r0 + lk * 4 + r;
      float v = acc[ct][r] + bs;
      if (RELU) v = fmaxf(v, 0.f);
      if (SCALE) v *= dvv[r];
      if (OUTF16) ((_Float16*)Cv)[(size_t)ro * M + col] = (_Float16)v;
      else        ((float*)Cv)[(size_t)ro * M + col] = v;
    }
  }
}

extern "C" void kernel_launch(void* const* d_in, const int* in_sizes, int n_in,
                              void* d_out, int out_size, void* d_ws, size_t ws_size,
                              hipStream_t stream) {
  const float* x  = (const float*)d_in[0];
  const int*   ei = (const int*)d_in[1];
  const float* W1 = (const float*)d_in[2];
  const float* b1 = (const float*)d_in[3];
  const float* W2 = (const float*)d_in[4];
  const float* b2 = (const float*)d_in[5];
  const float* W3 = (const float*)d_in[6];
  const float* b3 = (const float*)d_in[7];
  const float* W4 = (const float*)d_in[8];
  const float* b4 = (const float*)d_in[9];

  const int N = in_sizes[0] / 256;  // 50000
  const int E = in_sizes[1] / 2;    // 1600000
  const int* src = ei;
  const int* dst = ei + E;
  const int nb = cdiv(N, 64);       // 782 buckets

  const int NP = 50176;  // padded N
  int*   bh     = (int*)d_ws;                      // NBMAX
  int*   boff   = bh + NBMAX;                      // NBMAX
  int*   bcur   = boff + NBMAX;                    // NBMAX
  int*   counts = bcur + NBMAX;                    // NP
  int*   offs   = counts + NP;                     // NP
  float* dinv   = (float*)(offs + NP);             // NP
  unsigned short* esrc = (unsigned short*)(dinv + NP);  // E u16
  _Float16* W1t = (_Float16*)(esrc + E);           // 32768 halves
  _Float16* W2t = W1t + 32768;                     // 8192
  _Float16* W3t = W2t + 8192;                      // 8192
  _Float16* W4t = W3t + 8192;                      // 32768
  _Float16* bufA = (_Float16*)(((uintptr_t)(W4t + 32768) + 255) & ~(uintptr_t)255);
  _Float16* bufB = bufA + (size_t)N * 128;         // N*128 halves each
  _Float16* bufC = bufB + (size_t)N * 128;         // N*64 halves
  _Float16* bufD = bufC + (size_t)N * 64;          // N*64 halves
  unsigned* tmp = (unsigned*)bufA;  // E u32 overlay (dead before GEMM1 writes)
  float* out = (float*)d_out;

  dim3 blk(256);

  // --- weight transpose/cast (zeroes bh) + CSR build ---
  k_prepw<<<320, blk, 0, stream>>>(W1, W2, W3, W4, W1t, W2t, W3t, W4t, bh);
  {
    int nblk = 256;
    int perBlock = cdiv(E, nblk);
    k_bhist<<<nblk, blk, 0, stream>>>(dst, bh, E, nb, perBlock);
  }
  k_bscan<<<1, blk, 0, stream>>>(bh, boff, bcur, nb);
  k_bscatter<<<cdiv(E, SCHUNK), blk, 0, stream>>>(src, dst, bcur, tmp, E, nb);
  k_bsort<<<nb, blk, 0, stream>>>(tmp, boff, esrc, offs, counts, dinv, N);

  dim3 gpull(cdiv(N, 4));
  dim3 ggemm(cdiv(N, 16));  // 3125 blocks, every GEMM

  // L1: t1' = dinv o (x @ W1) -> bufA ; h1 = relu(dinv*acc + b1) -> bufB
  k_gemm_mfma<128, 256, 0, 0, 1, 1, 1><<<ggemm, blk, 0, stream>>>(x, W1t, nullptr, dinv, bufA, N);
  k_pull16<128, 1, 1, 0><<<gpull, blk, 0, stream>>>(bufA, esrc, offs, counts, dinv, b1, bufB, N);
  // L2: t2' = dinv o (h1 @ W2) -> bufC ; z' = dinv*relu(dinv*acc + b2) -> bufD
  k_gemm_mfma<64, 128, 0, 0, 1, 0, 1><<<ggemm, blk, 0, stream>>>(bufB, W2t, nullptr, dinv, bufC, N);
  k_pull16<64, 1, 1, 1><<<gpull, blk, 0, stream>>>(bufC, esrc, offs, counts, dinv, b2, bufD, N);
  // L3: p3 = dinv*acc(z') -> bufC ; h3' = dinv o relu(p3 @ W3 + b3) -> bufA
  k_pull16<64, 0, 0, 0><<<gpull, blk, 0, stream>>>(bufD, esrc, offs, counts, dinv, nullptr, bufC, N);
  k_gemm_mfma<128, 64, 1, 1, 1, 0, 1><<<ggemm, blk, 0, stream>>>(bufC, W3t, b3, dinv, bufA, N);
  // L4: p4 = dinv*acc(h3') -> bufB ; out = p4 @ W4 + b4 (fp32)
  k_pull16<128, 0, 0, 0><<<gpull, blk, 0, stream>>>(bufA, esrc, offs, counts, dinv, nullptr, bufB, N);
  k_gemm_mfma<256, 128, 1, 0, 0, 0, 0><<<ggemm, blk, 0, stream>>>(bufB, W4t, b4, nullptr, out, N);
}

// Round 15
// 287.549 us; speedup vs baseline: 1.2039x; 1.2039x over previous
//
#include <hip/hip_runtime.h>
#include <cstdint>
#include <cstddef>

// ---------------------------------------------------------------------------
// 4-layer GCN autoencoder, pull-based propagation + MFMA fp16 GEMMs.
// CSR built per launch with a 2-level counting sort (block-aggregated coarse
// scatter -> per-bucket LDS counting sort, u16 esrc).
// Propagation: out[d] = dinv[d]*sum_{s in N(d)u{d}} (dinv[s]*h[s]) (+b, relu);
// rows pre-scaled by dinv in the producer epilogue. All gathered/GEMM-input
// intermediates are fp16 (gather is L2-miss-byte-bound); accum fp32.
// GEMM (R14): LDS-staged (guide §5 structure). Block = 64 rows x M; the
// whole 64xK A-tile is reg-staged into LDS as fp16 (fp32 converts during
// staging; +16B row pad -> ds_read 2-way bank alias = free). Staging is 8
// independent coalesced loads/thread -> real MLP, decoupled from VGPRs
// (R11-R13 lesson: per-wave register prefetch is RA-capped at ~3 in flight).
// Each wave preloads its B-strip (ST x NT half8) ONCE and reuses it across
// 4 row-tiles of 16 rows. C/D map col=lane&15, row=(lane>>4)*4+reg.
// ---------------------------------------------------------------------------

static inline int cdiv(int a, int b) { return (a + b - 1) / b; }

typedef _Float16 half8v __attribute__((ext_vector_type(8)));
typedef float f32x4 __attribute__((ext_vector_type(4)));

#define NBMAX 784   // >= cdiv(50000,64)=782 buckets
#define SCHUNK 8192 // edges per scatter block

// coarse histogram over dst>>6 with LDS aggregation
__global__ __launch_bounds__(256) void k_bhist(const int* __restrict__ dst,
                                               int* __restrict__ bh,
                                               int E, int nb, int perBlock) {
  __shared__ int h[NBMAX];
  for (int i = threadIdx.x; i < nb; i += 256) h[i] = 0;
  __syncthreads();
  int beg = blockIdx.x * perBlock;
  int end = min(beg + perBlock, E);
  for (int e = beg + threadIdx.x; e < end; e += 256)
    atomicAdd(&h[dst[e] >> 6], 1);
  __syncthreads();
  for (int i = threadIdx.x; i < nb; i += 256)
    if (h[i]) atomicAdd(&bh[i], h[i]);
}

// single-block exclusive scan of nb (<=1024) bucket sums -> boff, bcur
__global__ __launch_bounds__(256) void k_bscan(const int* __restrict__ bh,
                                               int* __restrict__ boff,
                                               int* __restrict__ bcur, int nb) {
  __shared__ int tsum[256];
  int t = threadIdx.x;
  int v[4];
  int s = 0;
#pragma unroll
  for (int i = 0; i < 4; ++i) {
    int idx = t * 4 + i;
    v[i] = (idx < nb) ? bh[idx] : 0;
    s += v[i];
  }
  tsum[t] = s;
  __syncthreads();
  int x = s;
  for (int d = 1; d < 256; d <<= 1) {
    int add = (t >= d) ? tsum[t - d] : 0;
    __syncthreads();
    x += add;
    tsum[t] = x;
    __syncthreads();
  }
  int base = x - s;  // exclusive prefix
#pragma unroll
  for (int i = 0; i < 4; ++i) {
    int idx = t * 4 + i;
    if (idx < nb) { boff[idx] = base; bcur[idx] = base; }
    base += v[i];
  }
  if (t == 255) boff[nb] = base;  // == E
}

// block-aggregated coarse scatter: one global atomic per (block,bucket)
__global__ __launch_bounds__(256) void k_bscatter(const int* __restrict__ src,
                                                  const int* __restrict__ dst,
                                                  int* __restrict__ bcur,
                                                  unsigned* __restrict__ tmp,
                                                  int E, int nb) {
  __shared__ int hist[NBMAX];
  __shared__ int base[NBMAX];
  int beg = blockIdx.x * SCHUNK;
  int end = min(beg + SCHUNK, E);
  for (int i = threadIdx.x; i < nb; i += 256) hist[i] = 0;
  __syncthreads();
  for (int e = beg + threadIdx.x; e < end; e += 256)
    atomicAdd(&hist[dst[e] >> 6], 1);
  __syncthreads();
  for (int b = threadIdx.x; b < nb; b += 256) {
    int c = hist[b];
    base[b] = c ? atomicAdd(&bcur[b], c) : 0;
    hist[b] = 0;  // reuse as local cursor
  }
  __syncthreads();
  for (int e = beg + threadIdx.x; e < end; e += 256) {
    int d = dst[e];
    int b = d >> 6;
    int lp = atomicAdd(&hist[b], 1);
    tmp[base[b] + lp] = ((unsigned)(d & 63) << 16) | (unsigned)src[e];
  }
}

// per-bucket counting sort (64 bins in LDS); emits u16 esrc, counts/offs/dinv
__global__ __launch_bounds__(256) void k_bsort(const unsigned* __restrict__ tmp,
                                               const int* __restrict__ boff,
                                               unsigned short* __restrict__ esrc,
                                               int* __restrict__ offs,
                                               int* __restrict__ counts,
                                               float* __restrict__ dinv,
                                               int N) {
  __shared__ int hist[64], cur[64];
  int b = blockIdx.x;
  int t = threadIdx.x;
  if (t < 64) hist[t] = 0;
  __syncthreads();
  int beg = boff[b], end = boff[b + 1];
  int cnt = end - beg;
  for (int i = t; i < cnt; i += 256) atomicAdd(&hist[tmp[beg + i] >> 16], 1);
  __syncthreads();
  if (t < 64) {
    int v = hist[t];
    int x = v;
#pragma unroll
    for (int d = 1; d < 64; d <<= 1) {
      int up = __shfl_up(x, d, 64);
      if (t >= d) x += up;
    }
    int ex = x - v;
    cur[t] = ex;
    int node = b * 64 + t;
    if (node < N) {
      counts[node] = v;
      offs[node] = beg + ex;
      dinv[node] = rsqrtf((float)(v + 1));
    }
  }
  __syncthreads();
  for (int i = t; i < cnt; i += 256) {
    unsigned v = tmp[beg + i];
    int pos = atomicAdd(&cur[v >> 16], 1);
    esrc[beg + pos] = (unsigned short)(v & 0xFFFFu);
  }
}

// transpose+cast all weight matrices to fp16: Wt[m][k] = (fp16)W[k][m].
// Also zeroes bh (saves a memset dispatch; completes before k_bhist).
__global__ __launch_bounds__(256) void k_prepw(const float* __restrict__ W1,
                                               const float* __restrict__ W2,
                                               const float* __restrict__ W3,
                                               const float* __restrict__ W4,
                                               _Float16* __restrict__ W1t,
                                               _Float16* __restrict__ W2t,
                                               _Float16* __restrict__ W3t,
                                               _Float16* __restrict__ W4t,
                                               int* __restrict__ bh) {
  int t = blockIdx.x * 256 + threadIdx.x;
  if (t < NBMAX) bh[t] = 0;
  if (t < 32768) {                      // W1 [256][128] -> W1t [128][256]
    int m = t >> 8, k = t & 255;
    W1t[t] = (_Float16)W1[k * 128 + m];
  } else if (t < 40960) {               // W2 [128][64] -> W2t [64][128]
    int u = t - 32768;
    int m = u >> 7, k = u & 127;
    W2t[u] = (_Float16)W2[k * 64 + m];
  } else if (t < 49152) {               // W3 [64][128] -> W3t [128][64]
    int u = t - 40960;
    int m = u >> 6, k = u & 63;
    W3t[u] = (_Float16)W3[k * 128 + m];
  } else if (t < 81920) {               // W4 [128][256] -> W4t [256][128]
    int u = t - 49152;
    int m = u >> 7, k = u & 127;
    W4t[u] = (_Float16)W4[k * 256 + m];
  }
}

// fp16-gather pull. W = halves per row (128 or 64). One wave per node.
// LPR = W/8 lanes cover a row with 16B half8 loads; GRP = 64/LPR edges per
// wave instr (4 at w128, 8 at w64); 4-deep unroll for MLP.
// Epilogue (group 0): t = dinv*acc (+bias) (relu) (*dinv); fp16 output.
template <int W, int BIAS, int RELU, int POST>
__global__ __launch_bounds__(256) void k_pull16(const _Float16* __restrict__ h,
                                                const unsigned short* __restrict__ esrc,
                                                const int* __restrict__ offs,
                                                const int* __restrict__ counts,
                                                const float* __restrict__ dinv,
                                                const float* __restrict__ bias,
                                                _Float16* __restrict__ out, int n) {
  const int LPR = W / 8;    // lanes per row: 16 (w128) / 8 (w64)
  const int GRP = 64 / LPR; // edge groups:    4        / 8
  int node = blockIdx.x * 4 + (threadIdx.x >> 6);
  if (node >= n) return;
  int lane = threadIdx.x & 63;
  int g  = lane / LPR;
  int fl = lane % LPR;
  size_t rbase = (size_t)node * W + fl * 8;

  float acc[8] = {};
  if (g == 0) {
    half8v sv = *(const half8v*)&h[rbase];  // self loop
#pragma unroll
    for (int q = 0; q < 8; ++q) acc[q] = (float)sv[q];
  }

  int beg = offs[node];
  int cnt = counts[node];
  int j = g;
  for (; j + 3 * GRP < cnt; j += 4 * GRP) {
    int s0 = esrc[beg + j];
    int s1 = esrc[beg + j + GRP];
    int s2 = esrc[beg + j + 2 * GRP];
    int s3 = esrc[beg + j + 3 * GRP];
    half8v v0 = *(const half8v*)&h[(size_t)s0 * W + fl * 8];
    half8v v1 = *(const half8v*)&h[(size_t)s1 * W + fl * 8];
    half8v v2 = *(const half8v*)&h[(size_t)s2 * W + fl * 8];
    half8v v3 = *(const half8v*)&h[(size_t)s3 * W + fl * 8];
#pragma unroll
    for (int q = 0; q < 8; ++q)
      acc[q] += ((float)v0[q] + (float)v1[q]) + ((float)v2[q] + (float)v3[q]);
  }
  for (; j < cnt; j += GRP) {
    int s = esrc[beg + j];
    half8v v = *(const half8v*)&h[(size_t)s * W + fl * 8];
#pragma unroll
    for (int q = 0; q < 8; ++q) acc[q] += (float)v[q];
  }

  // reduce partial sums across edge-groups (same fl, different g)
#pragma unroll
  for (int d = LPR; d < 64; d <<= 1) {
#pragma unroll
    for (int q = 0; q < 8; ++q) acc[q] += __shfl_xor(acc[q], d, 64);
  }

  if (g == 0) {
    float dv = dinv[node];
    float t[8];
#pragma unroll
    for (int q = 0; q < 8; ++q) t[q] = dv * acc[q];
    if (BIAS) {
#pragma unroll
      for (int q = 0; q < 8; ++q) t[q] += bias[fl * 8 + q];
    }
    if (RELU) {
#pragma unroll
      for (int q = 0; q < 8; ++q) t[q] = fmaxf(t[q], 0.f);
    }
    if (POST) {
#pragma unroll
      for (int q = 0; q < 8; ++q) t[q] *= dv;
    }
    half8v o;
#pragma unroll
    for (int q = 0; q < 8; ++q) o[q] = (_Float16)t[q];
    *(half8v*)&out[rbase] = o;
  }
}

// LDS-staged MFMA fp16 GEMM: C[N,M] = A[N,K] @ W[K,M] (+bias)(+relu)(*dinv).
// Block = 64 rows x M; grid cdiv(N,64). Stage: whole 64xK A-tile -> LDS fp16
// (row stride K+8 halves = +16B pad; ds_read aliasing 2-way = free). Each
// wave owns cols [w*M/4, (w+1)*M/4): B-strip loaded once into regs (ST x NT
// half8, Wt L2-resident), reused across 4 row-tiles of 16 rows.
// AF32: A fp32->fp16 during staging. OUTF16: store fp16 else fp32.
template <int M, int K, int BIAS, int RELU, int SCALE, int AF32, int OUTF16>
__global__ __launch_bounds__(256) void k_gemm_mfma(const void* __restrict__ Av,
                                                   const _Float16* __restrict__ Wt,
                                                   const float* __restrict__ bias,
                                                   const float* __restrict__ dinv,
                                                   void* __restrict__ Cv, int N) {
  const int NT = M / 64;               // col-tiles per wave: 1,2,4
  const int ST = K / 32;               // k-steps: 2,4,8
  const int ROWW = K + 8;              // LDS row stride (halves): +16B pad
  __shared__ _Float16 Als[64 * ROWW];

  const int tid = threadIdx.x;
  const int r0 = blockIdx.x * 64;

  // ---- stage A tile (64 rows x K) into LDS as fp16 ----
  const int CH = K / 8;                // half8 chunks per row
  for (int i = tid; i < 64 * CH; i += 256) {
    int r = i / CH, c = i % CH;
    int gr = r0 + r;
    if (gr >= N) gr = N - 1;           // clamp: OOB rows never stored
    half8v v;
    if (AF32) {
      const float* ap = &((const float*)Av)[(size_t)gr * K + c * 8];
      float4 f0 = *(const float4*)ap;
      float4 f1 = *(const float4*)(ap + 4);
      v[0] = (_Float16)f0.x; v[1] = (_Float16)f0.y;
      v[2] = (_Float16)f0.z; v[3] = (_Float16)f0.w;
      v[4] = (_Float16)f1.x; v[5] = (_Float16)f1.y;
      v[6] = (_Float16)f1.z; v[7] = (_Float16)f1.w;
    } else {
      v = *(const half8v*)&((const _Float16*)Av)[(size_t)gr * K + c * 8];
    }
    *(half8v*)&Als[r * ROWW + c * 8] = v;
  }

  const int w  = tid >> 6;             // wave 0..3
  const int l  = tid & 63;
  const int lr = l & 15;               // A-row / B-col / C-col within tile
  const int lk = l >> 4;               // k-octet selector / C-row quad

  // ---- load this wave's B strip once (overlaps staging; Wt L2-resident) ----
  half8v b_all[ST][NT];
#pragma unroll
  for (int s = 0; s < ST; ++s)
#pragma unroll
    for (int ct = 0; ct < NT; ++ct) {
      int col0 = (w * NT + ct) * 16;
      b_all[s][ct] = *(const half8v*)&Wt[(size_t)(col0 + lr) * K + s * 32 + lk * 8];
    }

  __syncthreads();

  // ---- compute 4 row-tiles of 16 rows each ----
  for (int rt = 0; rt < 4; ++rt) {
    f32x4 acc[NT] = {};
#pragma unroll
    for (int s = 0; s < ST; ++s) {
      half8v a = *(const half8v*)&Als[(rt * 16 + lr) * ROWW + s * 32 + lk * 8];
#pragma unroll
      for (int ct = 0; ct < NT; ++ct)
        acc[ct] = __builtin_amdgcn_mfma_f32_16x16x32_f16(a, b_all[s][ct], acc[ct], 0, 0, 0);
    }

    // epilogue: C row = r0 + rt*16 + lk*4 + r, col = (w*NT+ct)*16 + lr
    int rbase = r0 + rt * 16;
    float dvv[4];
    int okr[4];
#pragma unroll
    for (int r = 0; r < 4; ++r) {
      int ro = rbase + lk * 4 + r;
      okr[r] = (ro < N);
      dvv[r] = (SCALE && okr[r]) ? dinv[ro] : 1.0f;
    }
#pragma unroll
    for (int ct = 0; ct < NT; ++ct) {
      int col = (w * NT + ct) * 16 + lr;
      float bs = BIAS ? bias[col] : 0.f;
#pragma unroll
      for (int r = 0; r < 4; ++r) {
        if (!okr[r]) continue;
        int ro = rbase + lk * 4 + r;
        float v = acc[ct][r] + bs;
        if (RELU) v = fmaxf(v, 0.f);
        if (SCALE) v *= dvv[r];
        if (OUTF16) ((_Float16*)Cv)[(size_t)ro * M + col] = (_Float16)v;
        else        ((float*)Cv)[(size_t)ro * M + col] = v;
      }
    }
  }
}

extern "C" void kernel_launch(void* const* d_in, const int* in_sizes, int n_in,
                              void* d_out, int out_size, void* d_ws, size_t ws_size,
                              hipStream_t stream) {
  const float* x  = (const float*)d_in[0];
  const int*   ei = (const int*)d_in[1];
  const float* W1 = (const float*)d_in[2];
  const float* b1 = (const float*)d_in[3];
  const float* W2 = (const float*)d_in[4];
  const float* b2 = (const float*)d_in[5];
  const float* W3 = (const float*)d_in[6];
  const float* b3 = (const float*)d_in[7];
  const float* W4 = (const float*)d_in[8];
  const float* b4 = (const float*)d_in[9];

  const int N = in_sizes[0] / 256;  // 50000
  const int E = in_sizes[1] / 2;    // 1600000
  const int* src = ei;
  const int* dst = ei + E;
  const int nb = cdiv(N, 64);       // 782 buckets

  const int NP = 50176;  // padded N
  int*   bh     = (int*)d_ws;                      // NBMAX
  int*   boff   = bh + NBMAX;                      // NBMAX
  int*   bcur   = boff + NBMAX;                    // NBMAX
  int*   counts = bcur + NBMAX;                    // NP
  int*   offs   = counts + NP;                     // NP
  float* dinv   = (float*)(offs + NP);             // NP
  unsigned short* esrc = (unsigned short*)(dinv + NP);  // E u16
  _Float16* W1t = (_Float16*)(esrc + E);           // 32768 halves
  _Float16* W2t = W1t + 32768;                     // 8192
  _Float16* W3t = W2t + 8192;                      // 8192
  _Float16* W4t = W3t + 8192;                      // 32768
  _Float16* bufA = (_Float16*)(((uintptr_t)(W4t + 32768) + 255) & ~(uintptr_t)255);
  _Float16* bufB = bufA + (size_t)N * 128;         // N*128 halves each
  _Float16* bufC = bufB + (size_t)N * 128;         // N*64 halves
  _Float16* bufD = bufC + (size_t)N * 64;          // N*64 halves
  unsigned* tmp = (unsigned*)bufA;  // E u32 overlay (dead before GEMM1 writes)
  float* out = (float*)d_out;

  dim3 blk(256);

  // --- weight transpose/cast (zeroes bh) + CSR build ---
  k_prepw<<<320, blk, 0, stream>>>(W1, W2, W3, W4, W1t, W2t, W3t, W4t, bh);
  {
    int nblk = 256;
    int perBlock = cdiv(E, nblk);
    k_bhist<<<nblk, blk, 0, stream>>>(dst, bh, E, nb, perBlock);
  }
  k_bscan<<<1, blk, 0, stream>>>(bh, boff, bcur, nb);
  k_bscatter<<<cdiv(E, SCHUNK), blk, 0, stream>>>(src, dst, bcur, tmp, E, nb);
  k_bsort<<<nb, blk, 0, stream>>>(tmp, boff, esrc, offs, counts, dinv, N);

  dim3 gpull(cdiv(N, 4));
  dim3 ggemm(cdiv(N, 64));  // 782 blocks, 64 rows each

  // L1: t1' = dinv o (x @ W1) -> bufA ; h1 = relu(dinv*acc + b1) -> bufB
  k_gemm_mfma<128, 256, 0, 0, 1, 1, 1><<<ggemm, blk, 0, stream>>>(x, W1t, nullptr, dinv, bufA, N);
  k_pull16<128, 1, 1, 0><<<gpull, blk, 0, stream>>>(bufA, esrc, offs, counts, dinv, b1, bufB, N);
  // L2: t2' = dinv o (h1 @ W2) -> bufC ; z' = dinv*relu(dinv*acc + b2) -> bufD
  k_gemm_mfma<64, 128, 0, 0, 1, 0, 1><<<ggemm, blk, 0, stream>>>(bufB, W2t, nullptr, dinv, bufC, N);
  k_pull16<64, 1, 1, 1><<<gpull, blk, 0, stream>>>(bufC, esrc, offs, counts, dinv, b2, bufD, N);
  // L3: p3 = dinv*acc(z') -> bufC ; h3' = dinv o relu(p3 @ W3 + b3) -> bufA
  k_pull16<64, 0, 0, 0><<<gpull, blk, 0, stream>>>(bufD, esrc, offs, counts, dinv, nullptr, bufC, N);
  k_gemm_mfma<128, 64, 1, 1, 1, 0, 1><<<ggemm, blk, 0, stream>>>(bufC, W3t, b3, dinv, bufA, N);
  // L4: p4 = dinv*acc(h3') -> bufB ; out = p4 @ W4 + b4 (fp32)
  k_pull16<128, 0, 0, 0><<<gpull, blk, 0, stream>>>(bufA, esrc, offs, counts, dinv, nullptr, bufB, N);
  k_gemm_mfma<256, 128, 1, 0, 0, 0, 0><<<ggemm, blk, 0, stream>>>(bufB, W4t, b4, nullptr, out, N);
}